// Round 4
// baseline (37877.444 us; speedup 1.0000x reference)
//
#include <hip/hip_runtime.h>

typedef _Float16 f16;
typedef _Float16 h2 __attribute__((ext_vector_type(2)));
typedef _Float16 h8 __attribute__((ext_vector_type(8)));
typedef float f4 __attribute__((ext_vector_type(4)));

constexpr int Bb = 64, Tt = 2048, Xx = 128, Hh = 256, G4 = 1024, Z2 = 128;

__device__ __forceinline__ float fdot2f(h2 a, h2 b, float c) {
#if __has_builtin(__builtin_amdgcn_fdot2)
  return __builtin_amdgcn_fdot2(a, b, c, false);
#else
  return c + (float)a[0] * (float)b[0] + (float)a[1] * (float)b[1];
#endif
}
__device__ __forceinline__ float sigmf(float x) {
  float e = __expf(-x);
  return __builtin_amdgcn_rcpf(1.0f + e);
}
__device__ __forceinline__ float tanhf_(float x) {
  float e = __expf(2.0f * x);
  return 1.0f - 2.0f * __builtin_amdgcn_rcpf(e + 1.0f);
}
__device__ __forceinline__ h2 bch2(unsigned int u) { return __builtin_bit_cast(h2, u); }

// ---------------- casts ----------------
__global__ void cast_f16_k(const float* __restrict__ in, f16* __restrict__ out, int n) {
  int i = (blockIdx.x * 256 + threadIdx.x) * 4;
  if (i >= n) return;
  float4 v = *(const float4*)(in + i);
  h2 a = {(f16)v.x, (f16)v.y};
  h2 b = {(f16)v.z, (f16)v.w};
  uint2 o = {__builtin_bit_cast(unsigned int, a), __builtin_bit_cast(unsigned int, b)};
  *(uint2*)(out + i) = o;
}

// Wh (H=256, 4H=1024) fp32 -> WhT (1024, 256) f16, writes coalesced
__global__ void cast_whT_k(const float* __restrict__ Wh, f16* __restrict__ WhT) {
  int idx = blockIdx.x * 256 + threadIdx.x;  // 262144 = G4*Hh, WhT-linear
  int g = idx >> 8, k = idx & 255;
  WhT[idx] = (f16)Wh[(long)k * G4 + g];
}

// ---------------- generic f16 MFMA GEMM, 64x64 tile ----------------
__global__ __launch_bounds__(256, 4) void gemm_f16_k(
    const f16* __restrict__ A, const f16* __restrict__ Bm, const float* __restrict__ bias,
    f16* __restrict__ C16, float* __restrict__ Cmu, float* __restrict__ Cls,
    int N, int K, int a_shift, int a_ostride, int a_t0,
    int mode, int o_t0, int tcshift)
{
  __shared__ __align__(16) f16 At[64][48];
  __shared__ __align__(16) f16 Bt[64][48];
  const int tid = threadIdx.x;
  const int mblk = blockIdx.x, nblk = blockIdx.y;
  const int w = tid >> 6, lane = tid & 63;

  const int sa_row = tid >> 2, sa_k = (tid & 3) * 8;
  const int m_g = mblk * 64 + sa_row;
  const long arow = (long)(m_g >> a_shift) * a_ostride + a_t0 + (m_g & ((1 << a_shift) - 1));
  const f16* aptr = A + arow * K + sa_k;
  const int sb_k = tid >> 3, sb_n = (tid & 7) * 8;
  const f16* bptr = Bm + (long)sb_k * N + nblk * 64 + sb_n;

  f4 acc[4];
#pragma unroll
  for (int i = 0; i < 4; ++i) acc[i] = (f4){0.f, 0.f, 0.f, 0.f};

  const int arow_l = w * 16 + (lane & 15);
  const int k0 = (lane >> 4) * 8;

  for (int kk = 0; kk < K; kk += 32) {
    uint4 av = *(const uint4*)(aptr + kk);
    uint4 bv = *(const uint4*)(bptr + (long)kk * N);
    __syncthreads();
    *(uint4*)&At[sa_row][sa_k] = av;
    h8 bx = __builtin_bit_cast(h8, bv);
#pragma unroll
    for (int j = 0; j < 8; ++j) Bt[sb_n + j][sb_k] = bx[j];
    __syncthreads();
    h8 af = *(const h8*)&At[arow_l][k0];
#pragma unroll
    for (int nt = 0; nt < 4; ++nt) {
      h8 bf = *(const h8*)&Bt[nt * 16 + (lane & 15)][k0];
      acc[nt] = __builtin_amdgcn_mfma_f32_16x16x32_f16(af, bf, acc[nt], 0, 0, 0);
    }
  }

  const int row_l = w * 16 + ((lane >> 4) << 2);
  const int col_l = lane & 15;
#pragma unroll
  for (int nt = 0; nt < 4; ++nt) {
    int gcol = nblk * 64 + nt * 16 + col_l;
    float bv = bias[gcol];
#pragma unroll
    for (int r = 0; r < 4; ++r) {
      int gm = mblk * 64 + row_l + r;
      float val = acc[nt][r] + bv;
      if (mode == 1) val = fmaxf(val, 0.f);
      if (mode <= 1) {
        C16[(long)gm * N + gcol] = (f16)val;
      } else {
        int bb = gm >> tcshift, tl = gm & ((1 << tcshift) - 1);
        long orow = (long)bb * Tt + o_t0 + tl;
        if (gcol < 64) Cmu[orow * 64 + gcol] = val;
        else Cls[orow * 64 + (gcol - 64)] = val;
      }
    }
  }
}

// ---------------- persistent-weight LSTM scan ----------------
// 512 threads = 8 waves = 2 waves/SIMD -> 256-reg unified budget per wave.
// Thread tid owns gate columns g0=tid, g1=tid+512:
//   tid<256: (i_j, g_j), j=tid | tid>=256: (f_j, o_j) + cell c_j, j=tid-256.
// Weight head (K<184, 92 h2 per column, 184 total) lives in explicit AGPRs
// via v_accvgpr_write/read inline asm: the allocator refused >128 arch VGPRs
// in rounds 1-2 (spill -> 8us/step); AGPR class sidesteps that deterministically.
// volatile reads prevent LICM hoisting the (loop-invariant) weights back into
// VGPRs. Weight tail (K in [184,256), 36 h2/col) in LDS, b128 full-BW layout.
__global__ void __launch_bounds__(512) __attribute__((amdgpu_waves_per_eu(1, 2)))
lstm_rec_k(
    const f16* __restrict__ WhT, const f16* __restrict__ xp,
    f16* __restrict__ hout, float* __restrict__ c_state, f16* __restrict__ h_state,
    int TC, int first)
{
  const int b = blockIdx.x, tid = threadIdx.x;
  const int g0 = tid, g1 = tid + 512;
  __shared__ __align__(16) h2 hbuf[128];      // h_t: 128 f16 pairs (512 B)
  __shared__ float pbuf[256];                 // sig(i)*tanh(g) (1 KB)
  __shared__ __align__(16) h2 wlds[9][1024][4]; // tail: 9 groups x col x 4 h2 = 144 KB

  int wA[92], wB[92];  // h2 pairs bitcast to int, pinned to AGPRs below
  {
    const uint4* p0 = (const uint4*)(WhT + (long)g0 * Hh);
    const uint4* p1 = (const uint4*)(WhT + (long)g1 * Hh);
#pragma unroll
    for (int i = 0; i < 23; ++i) {
      uint4 v = p0[i];
      asm("v_accvgpr_write_b32 %0, %1" : "=a"(wA[4 * i + 0]) : "v"(v.x));
      asm("v_accvgpr_write_b32 %0, %1" : "=a"(wA[4 * i + 1]) : "v"(v.y));
      asm("v_accvgpr_write_b32 %0, %1" : "=a"(wA[4 * i + 2]) : "v"(v.z));
      asm("v_accvgpr_write_b32 %0, %1" : "=a"(wA[4 * i + 3]) : "v"(v.w));
    }
#pragma unroll
    for (int i = 0; i < 23; ++i) {
      uint4 v = p1[i];
      asm("v_accvgpr_write_b32 %0, %1" : "=a"(wB[4 * i + 0]) : "v"(v.x));
      asm("v_accvgpr_write_b32 %0, %1" : "=a"(wB[4 * i + 1]) : "v"(v.y));
      asm("v_accvgpr_write_b32 %0, %1" : "=a"(wB[4 * i + 2]) : "v"(v.z));
      asm("v_accvgpr_write_b32 %0, %1" : "=a"(wB[4 * i + 3]) : "v"(v.w));
    }
#pragma unroll
    for (int g = 0; g < 9; ++g) {
      *(uint4*)&wlds[g][g0][0] = p0[23 + g];
      *(uint4*)&wlds[g][g1][0] = p1[23 + g];
    }
  }

  float c = 0.f;
  if (tid >= 256 && !first) c = c_state[b * Hh + (tid - 256)];
  if (tid < 128) {
    h2 hz = {(f16)0.f, (f16)0.f};
    hbuf[tid] = first ? hz : ((const h2*)h_state)[b * 128 + tid];
  }
  __syncthreads();

  const f16* xprow = xp + (long)b * TC * G4;
  f16 xc0 = xprow[g0], xc1 = xprow[g1];
  for (int t = 0; t < TC; ++t) {
    int tn = (t + 1 < TC) ? t + 1 : t;
    f16 xn0 = xprow[(long)tn * G4 + g0];   // prefetch next step's x-projection
    f16 xn1 = xprow[(long)tn * G4 + g1];

    float a0 = (float)xc0, a1 = (float)xc1;   // bh folded into xp already
    const uint4* hb4 = (const uint4*)hbuf;
#pragma unroll
    for (int i = 0; i < 23; ++i) {
      uint4 hv = hb4[i];   // b128 broadcast read of 4 h2
      int t0, t1, t2, t3, u0, u1, u2, u3;
      asm volatile("v_accvgpr_read_b32 %0, %1" : "=v"(t0) : "a"(wA[4 * i + 0]));
      asm volatile("v_accvgpr_read_b32 %0, %1" : "=v"(t1) : "a"(wA[4 * i + 1]));
      asm volatile("v_accvgpr_read_b32 %0, %1" : "=v"(t2) : "a"(wA[4 * i + 2]));
      asm volatile("v_accvgpr_read_b32 %0, %1" : "=v"(t3) : "a"(wA[4 * i + 3]));
      asm volatile("v_accvgpr_read_b32 %0, %1" : "=v"(u0) : "a"(wB[4 * i + 0]));
      asm volatile("v_accvgpr_read_b32 %0, %1" : "=v"(u1) : "a"(wB[4 * i + 1]));
      asm volatile("v_accvgpr_read_b32 %0, %1" : "=v"(u2) : "a"(wB[4 * i + 2]));
      asm volatile("v_accvgpr_read_b32 %0, %1" : "=v"(u3) : "a"(wB[4 * i + 3]));
      a0 = fdot2f(bch2((unsigned)t0), bch2(hv.x), a0);
      a1 = fdot2f(bch2((unsigned)u0), bch2(hv.x), a1);
      a0 = fdot2f(bch2((unsigned)t1), bch2(hv.y), a0);
      a1 = fdot2f(bch2((unsigned)u1), bch2(hv.y), a1);
      a0 = fdot2f(bch2((unsigned)t2), bch2(hv.z), a0);
      a1 = fdot2f(bch2((unsigned)u2), bch2(hv.z), a1);
      a0 = fdot2f(bch2((unsigned)t3), bch2(hv.w), a0);
      a1 = fdot2f(bch2((unsigned)u3), bch2(hv.w), a1);
    }
#pragma unroll
    for (int g = 0; g < 9; ++g) {
      uint4 ht = hb4[23 + g];                       // broadcast h tail
      uint4 wa = *(const uint4*)&wlds[g][g0][0];    // full-BW b128, 16B/lane
      uint4 wb = *(const uint4*)&wlds[g][g1][0];
      a0 = fdot2f(bch2(wa.x), bch2(ht.x), a0);
      a1 = fdot2f(bch2(wb.x), bch2(ht.x), a1);
      a0 = fdot2f(bch2(wa.y), bch2(ht.y), a0);
      a1 = fdot2f(bch2(wb.y), bch2(ht.y), a1);
      a0 = fdot2f(bch2(wa.z), bch2(ht.z), a0);
      a1 = fdot2f(bch2(wb.z), bch2(ht.z), a1);
      a0 = fdot2f(bch2(wa.w), bch2(ht.w), a0);
      a1 = fdot2f(bch2(wb.w), bch2(ht.w), a1);
    }

    float v0 = 0.f, v1 = 0.f;
    if (tid < 256) {
      pbuf[tid] = sigmf(a0) * tanhf_(a1);   // sig(i)*tanh(g)
    } else {
      v0 = sigmf(a0);                        // sig(f)
      v1 = sigmf(a1);                        // sig(o)
    }
    __syncthreads();
    if (tid >= 256) {
      int j = tid - 256;
      c = v0 * c + pbuf[j];
      float hval = v1 * tanhf_(c);
      f16 hh = (f16)hval;
      ((f16*)hbuf)[j] = hh;
      hout[((long)b * TC + t) * Hh + j] = hh;
    }
    __syncthreads();
    xc0 = xn0; xc1 = xn1;
  }
  if (tid >= 256) c_state[b * Hh + (tid - 256)] = c;
  if (tid < 128) ((h2*)h_state)[b * 128 + tid] = hbuf[tid];
}

// ---------------- host ----------------
extern "C" void kernel_launch(void* const* d_in, const int* in_sizes, int n_in,
                              void* d_out, int out_size, void* d_ws, size_t ws_size,
                              hipStream_t stream)
{
  const float* x  = (const float*)d_in[0];
  const float* Wi = (const float*)d_in[1];
  const float* Wh = (const float*)d_in[2];
  const float* bh = (const float*)d_in[3];
  const float* W1 = (const float*)d_in[4];
  const float* b1 = (const float*)d_in[5];
  const float* W2 = (const float*)d_in[6];
  const float* b2 = (const float*)d_in[7];
  float* out = (float*)d_out;

  char* ws = (char*)d_ws;
  size_t off = 0;
  auto alloc = [&](size_t bytes) -> char* {
    char* p = ws + off;
    off = (off + bytes + 255) & ~(size_t)255;
    return p;
  };
  f16* x16   = (f16*)alloc((size_t)Bb * Tt * Xx * 2);
  f16* wi16  = (f16*)alloc((size_t)Xx * G4 * 2);
  f16* whT16 = (f16*)alloc((size_t)G4 * Hh * 2);
  f16* w116  = (f16*)alloc((size_t)Hh * Hh * 2);
  f16* w216  = (f16*)alloc((size_t)Hh * Z2 * 2);
  float* cst = (float*)alloc((size_t)Bb * Hh * 4);
  f16* hst   = (f16*)alloc((size_t)Bb * Hh * 2);

  int tc = 2048;
  while (tc > 32) {
    size_t need = (size_t)Bb * tc * G4 * 2 + (size_t)Bb * tc * Hh * 2;
    if (off + need <= ws_size) break;
    tc >>= 1;
  }
  int tcsh = __builtin_ctz((unsigned)tc);
  f16* xp16 = (f16*)alloc((size_t)Bb * tc * G4 * 2);
  f16* h16  = (f16*)alloc((size_t)Bb * tc * Hh * 2);
  f16* hid16 = xp16;  // head hidden aliases xp (xp fully consumed by the scan)

  cast_f16_k<<<(Bb * Tt * Xx) / 1024, 256, 0, stream>>>(x, x16, Bb * Tt * Xx);
  cast_f16_k<<<(Xx * G4) / 1024, 256, 0, stream>>>(Wi, wi16, Xx * G4);
  cast_f16_k<<<(Hh * Hh) / 1024, 256, 0, stream>>>(W1, w116, Hh * Hh);
  cast_f16_k<<<(Hh * Z2) / 1024, 256, 0, stream>>>(W2, w216, Hh * Z2);
  cast_whT_k<<<(Hh * G4) / 256, 256, 0, stream>>>(Wh, whT16);

  float* mu = out;
  float* ls = out + (size_t)Bb * Tt * 64;

  for (int t0 = 0; t0 < Tt; t0 += tc) {
    dim3 gx(Bb * tc / 64, G4 / 64);
    gemm_f16_k<<<gx, 256, 0, stream>>>(x16, wi16, bh, xp16, nullptr, nullptr,
                                       G4, Xx, tcsh, Tt, t0, 0, 0, 0);
    lstm_rec_k<<<Bb, 512, 0, stream>>>(whT16, xp16, h16, cst, hst, tc, (t0 == 0) ? 1 : 0);
    dim3 g1g(Bb * tc / 64, Hh / 64);
    gemm_f16_k<<<g1g, 256, 0, stream>>>(h16, w116, b1, hid16, nullptr, nullptr,
                                        Hh, Hh, 30, 0, 0, 1, 0, 0);
    dim3 g2g(Bb * tc / 64, Z2 / 64);
    gemm_f16_k<<<g2g, 256, 0, stream>>>(hid16, w216, b2, nullptr, mu, ls,
                                        Z2, Hh, 30, 0, 0, 2, t0, tcsh);
  }
}

// Round 5
// 3596.926 us; speedup vs baseline: 10.5305x; 10.5305x over previous
//
#include <hip/hip_runtime.h>

typedef _Float16 f16;
typedef _Float16 h2 __attribute__((ext_vector_type(2)));
typedef _Float16 h8 __attribute__((ext_vector_type(8)));
typedef float f4 __attribute__((ext_vector_type(4)));

constexpr int Bb = 64, Tt = 2048, Xx = 128, Hh = 256, G4 = 1024, Z2 = 128;

__device__ __forceinline__ float fdot2f(h2 a, h2 b, float c) {
#if __has_builtin(__builtin_amdgcn_fdot2)
  return __builtin_amdgcn_fdot2(a, b, c, false);
#else
  return c + (float)a[0] * (float)b[0] + (float)a[1] * (float)b[1];
#endif
}
__device__ __forceinline__ float tanhf_(float x) {
  float e = __expf(2.0f * x);
  return 1.0f - 2.0f * __builtin_amdgcn_rcpf(e + 1.0f);
}
__device__ __forceinline__ h2 bch2(unsigned int u) { return __builtin_bit_cast(h2, u); }

template <int CTRL>
__device__ __forceinline__ float qb(float v) {  // quad_perm broadcast
  return __builtin_bit_cast(float,
      __builtin_amdgcn_mov_dpp(__builtin_bit_cast(int, v), CTRL, 0xf, 0xf, true));
}

// ---------------- casts ----------------
__global__ void cast_f16_k(const float* __restrict__ in, f16* __restrict__ out, int n) {
  int i = (blockIdx.x * 256 + threadIdx.x) * 4;
  if (i >= n) return;
  float4 v = *(const float4*)(in + i);
  h2 a = {(f16)v.x, (f16)v.y};
  h2 b = {(f16)v.z, (f16)v.w};
  uint2 o = {__builtin_bit_cast(unsigned int, a), __builtin_bit_cast(unsigned int, b)};
  *(uint2*)(out + i) = o;
}

// Wh (256,1024) fp32 -> WhT (1024,256) f16, rows in quad-gate thread order:
// thread tid owns gate (tid&3) of column (tid>>2)  ->  gcol = ((r&3)<<8)|(r>>2)
__global__ void cast_whT_k(const float* __restrict__ Wh, f16* __restrict__ WhT) {
  int idx = blockIdx.x * 256 + threadIdx.x;  // 262144 = G4*Hh, WhT-linear
  int r = idx >> 8, k = idx & 255;
  int gcol = ((r & 3) << 8) | (r >> 2);
  WhT[idx] = (f16)Wh[(long)k * G4 + gcol];
}

// ---------------- generic f16 MFMA GEMM, 64x64 tile ----------------
__global__ __launch_bounds__(256, 4) void gemm_f16_k(
    const f16* __restrict__ A, const f16* __restrict__ Bm, const float* __restrict__ bias,
    f16* __restrict__ C16, float* __restrict__ Cmu, float* __restrict__ Cls,
    int N, int K, int a_shift, int a_ostride, int a_t0,
    int mode, int o_t0, int tcshift)
{
  __shared__ __align__(16) f16 At[64][48];
  __shared__ __align__(16) f16 Bt[64][48];
  const int tid = threadIdx.x;
  const int mblk = blockIdx.x, nblk = blockIdx.y;
  const int w = tid >> 6, lane = tid & 63;

  const int sa_row = tid >> 2, sa_k = (tid & 3) * 8;
  const int m_g = mblk * 64 + sa_row;
  const long arow = (long)(m_g >> a_shift) * a_ostride + a_t0 + (m_g & ((1 << a_shift) - 1));
  const f16* aptr = A + arow * K + sa_k;
  const int sb_k = tid >> 3, sb_n = (tid & 7) * 8;
  const f16* bptr = Bm + (long)sb_k * N + nblk * 64 + sb_n;

  f4 acc[4];
#pragma unroll
  for (int i = 0; i < 4; ++i) acc[i] = (f4){0.f, 0.f, 0.f, 0.f};

  const int arow_l = w * 16 + (lane & 15);
  const int k0 = (lane >> 4) * 8;

  for (int kk = 0; kk < K; kk += 32) {
    uint4 av = *(const uint4*)(aptr + kk);
    uint4 bv = *(const uint4*)(bptr + (long)kk * N);
    __syncthreads();
    *(uint4*)&At[sa_row][sa_k] = av;
    h8 bx = __builtin_bit_cast(h8, bv);
#pragma unroll
    for (int j = 0; j < 8; ++j) Bt[sb_n + j][sb_k] = bx[j];
    __syncthreads();
    h8 af = *(const h8*)&At[arow_l][k0];
#pragma unroll
    for (int nt = 0; nt < 4; ++nt) {
      h8 bf = *(const h8*)&Bt[nt * 16 + (lane & 15)][k0];
      acc[nt] = __builtin_amdgcn_mfma_f32_16x16x32_f16(af, bf, acc[nt], 0, 0, 0);
    }
  }

  const int row_l = w * 16 + ((lane >> 4) << 2);
  const int col_l = lane & 15;
#pragma unroll
  for (int nt = 0; nt < 4; ++nt) {
    int gcol = nblk * 64 + nt * 16 + col_l;
    float bv = bias[gcol];
#pragma unroll
    for (int r = 0; r < 4; ++r) {
      int gm = mblk * 64 + row_l + r;
      float val = acc[nt][r] + bv;
      if (mode == 1) val = fmaxf(val, 0.f);
      if (mode <= 1) {
        C16[(long)gm * N + gcol] = (f16)val;
      } else {
        int bb = gm >> tcshift, tl = gm & ((1 << tcshift) - 1);
        long orow = (long)bb * Tt + o_t0 + tl;
        if (gcol < 64) Cmu[orow * 64 + gcol] = val;
        else Cls[orow * 64 + (gcol - 64)] = val;
      }
    }
  }
}

// ---------------- persistent-weight LSTM scan (quad-gate) ----------------
// 1024 threads/block (round-3 register regime: plain w[96] array got
// auto-promoted to AGPRs, VGPR_Count=64, zero scratch -- keep that shape).
// Thread tid: column j = tid>>2, gate = tid&3 (0=i,1=f,2=g,3=o), so all four
// gates of a column live in one LANE QUAD: gate exchange = 4 dpp quad_perm
// movs in-register (round 3 paid pbuf store + 2 barriers + a 12-idle-wave
// serial phase for this). hbuf double-buffered -> ONE barrier per step.
// Weights: k<192 in w[96] (AGPR-promoted), k in [192,256) in LDS as 8 b128
// reads (round 3: 16 b64). Tail-h reads fold into the 32 hbuf broadcasts.
__global__ void __launch_bounds__(1024) __attribute__((amdgpu_waves_per_eu(4, 4)))
lstm_rec_k(
    const f16* __restrict__ WhT, const f16* __restrict__ xp,
    f16* __restrict__ hout, float* __restrict__ c_state, f16* __restrict__ h_state,
    int TC, int first)
{
  const int b = blockIdx.x, tid = threadIdx.x;
  const int j = tid >> 2, g = tid & 3;
  __shared__ __align__(16) h2 hbuf[2][128];   // double-buffered h_t (1 KB)
  __shared__ __align__(16) h2 wlds[8][1024][4]; // weight tail k in [192,256): 128 KB

  h2 w[96];
  {
    const uint4* p4 = (const uint4*)(WhT + (long)tid * Hh);
#pragma unroll
    for (int i = 0; i < 24; ++i) {
      uint4 v = p4[i];
      w[4 * i + 0] = bch2(v.x); w[4 * i + 1] = bch2(v.y);
      w[4 * i + 2] = bch2(v.z); w[4 * i + 3] = bch2(v.w);
    }
#pragma unroll
    for (int gg = 0; gg < 8; ++gg) *(uint4*)&wlds[gg][tid][0] = p4[24 + gg];
  }

  float c = first ? 0.f : c_state[b * Hh + j];   // all 4 quad lanes hold c_j
  if (tid < 128) {
    h2 hz = {(f16)0.f, (f16)0.f};
    hbuf[0][tid] = first ? hz : ((const h2*)h_state)[b * 128 + tid];
  }
  __syncthreads();

  const float sgn = (g == 2) ? 2.0f : -1.0f;     // tanh vs sigmoid exponent sign
  const f16* xprow = xp + (long)b * TC * G4;     // xp stays gate-major: row (g<<8)|j
  const int xcol = (g << 8) | j;
  f16 xc = xprow[xcol];
  int p = 0;
  for (int t = 0; t < TC; ++t) {
    int tn = (t + 1 < TC) ? t + 1 : t;
    f16 xn = xprow[(long)tn * G4 + xcol];        // prefetch next step

    float a0 = (float)xc, a1 = 0.f;              // bh folded into xp already
    const uint4* hb4 = (const uint4*)&hbuf[p][0];
#pragma unroll
    for (int i = 0; i < 24; ++i) {
      uint4 hv = hb4[i];                          // b128 broadcast (4 h2)
      a0 = fdot2f(w[4 * i + 0], bch2(hv.x), a0);
      a1 = fdot2f(w[4 * i + 1], bch2(hv.y), a1);
      a0 = fdot2f(w[4 * i + 2], bch2(hv.z), a0);
      a1 = fdot2f(w[4 * i + 3], bch2(hv.w), a1);
    }
#pragma unroll
    for (int gg = 0; gg < 8; ++gg) {
      uint4 hv = hb4[24 + gg];                    // tail h broadcast
      uint4 wv = *(const uint4*)&wlds[gg][tid][0]; // per-lane b128, conflict-free
      a0 = fdot2f(bch2(wv.x), bch2(hv.x), a0);
      a1 = fdot2f(bch2(wv.y), bch2(hv.y), a1);
      a0 = fdot2f(bch2(wv.z), bch2(hv.z), a0);
      a1 = fdot2f(bch2(wv.w), bch2(hv.w), a1);
    }
    float a = a0 + a1;

    // unified activation: e = exp(sgn*a); sig = 1/(1+e), tanh = 1 - 2/(1+e)
    float e = __expf(sgn * a);
    float r = __builtin_amdgcn_rcpf(1.0f + e);
    float act = (g == 2) ? 1.0f - 2.0f * r : r;

    float ai = qb<0x00>(act), af = qb<0x55>(act);
    float ag = qb<0xAA>(act), ao = qb<0xFF>(act);
    c = af * c + ai * ag;
    float hval = ao * tanhf_(c);
    if (g == 3) {
      f16 hh = (f16)hval;
      ((f16*)&hbuf[p ^ 1][0])[j] = hh;
      hout[((long)b * TC + t) * Hh + j] = hh;
    }
    __syncthreads();
    p ^= 1;
    xc = xn;
  }
  if (g == 0) c_state[b * Hh + j] = c;
  if (tid < 128) ((h2*)h_state)[b * 128 + tid] = hbuf[p][tid];
}

// ---------------- host ----------------
extern "C" void kernel_launch(void* const* d_in, const int* in_sizes, int n_in,
                              void* d_out, int out_size, void* d_ws, size_t ws_size,
                              hipStream_t stream)
{
  const float* x  = (const float*)d_in[0];
  const float* Wi = (const float*)d_in[1];
  const float* Wh = (const float*)d_in[2];
  const float* bh = (const float*)d_in[3];
  const float* W1 = (const float*)d_in[4];
  const float* b1 = (const float*)d_in[5];
  const float* W2 = (const float*)d_in[6];
  const float* b2 = (const float*)d_in[7];
  float* out = (float*)d_out;

  char* ws = (char*)d_ws;
  size_t off = 0;
  auto alloc = [&](size_t bytes) -> char* {
    char* p = ws + off;
    off = (off + bytes + 255) & ~(size_t)255;
    return p;
  };
  f16* x16   = (f16*)alloc((size_t)Bb * Tt * Xx * 2);
  f16* wi16  = (f16*)alloc((size_t)Xx * G4 * 2);
  f16* whT16 = (f16*)alloc((size_t)G4 * Hh * 2);
  f16* w116  = (f16*)alloc((size_t)Hh * Hh * 2);
  f16* w216  = (f16*)alloc((size_t)Hh * Z2 * 2);
  float* cst = (float*)alloc((size_t)Bb * Hh * 4);
  f16* hst   = (f16*)alloc((size_t)Bb * Hh * 2);

  int tc = 2048;
  while (tc > 32) {
    size_t need = (size_t)Bb * tc * G4 * 2 + (size_t)Bb * tc * Hh * 2;
    if (off + need <= ws_size) break;
    tc >>= 1;
  }
  int tcsh = __builtin_ctz((unsigned)tc);
  f16* xp16 = (f16*)alloc((size_t)Bb * tc * G4 * 2);
  f16* h16  = (f16*)alloc((size_t)Bb * tc * Hh * 2);
  f16* hid16 = xp16;  // head hidden aliases xp (xp fully consumed by the scan)

  cast_f16_k<<<(Bb * Tt * Xx) / 1024, 256, 0, stream>>>(x, x16, Bb * Tt * Xx);
  cast_f16_k<<<(Xx * G4) / 1024, 256, 0, stream>>>(Wi, wi16, Xx * G4);
  cast_f16_k<<<(Hh * Hh) / 1024, 256, 0, stream>>>(W1, w116, Hh * Hh);
  cast_f16_k<<<(Hh * Z2) / 1024, 256, 0, stream>>>(W2, w216, Hh * Z2);
  cast_whT_k<<<(Hh * G4) / 256, 256, 0, stream>>>(Wh, whT16);

  float* mu = out;
  float* ls = out + (size_t)Bb * Tt * 64;

  for (int t0 = 0; t0 < Tt; t0 += tc) {
    dim3 gx(Bb * tc / 64, G4 / 64);
    gemm_f16_k<<<gx, 256, 0, stream>>>(x16, wi16, bh, xp16, nullptr, nullptr,
                                       G4, Xx, tcsh, Tt, t0, 0, 0, 0);
    lstm_rec_k<<<Bb, 1024, 0, stream>>>(whT16, xp16, h16, cst, hst, tc, (t0 == 0) ? 1 : 0);
    dim3 g1g(Bb * tc / 64, Hh / 64);
    gemm_f16_k<<<g1g, 256, 0, stream>>>(h16, w116, b1, hid16, nullptr, nullptr,
                                        Hh, Hh, 30, 0, 0, 1, 0, 0);
    dim3 g2g(Bb * tc / 64, Z2 / 64);
    gemm_f16_k<<<g2g, 256, 0, stream>>>(hid16, w216, b2, nullptr, mu, ls,
                                        Z2, Hh, 30, 0, 0, 2, t0, tcsh);
  }
}